// Round 1
// baseline (116.437 us; speedup 1.0000x reference)
//
#include <hip/hip_runtime.h>

#define NW 8
#define S_ 1024
#define H_ 8
#define B_ 8
#define BH 64           // B*H
#define NTH 65536       // B*S*H
#define NROW 8192       // B*S
#define E_ 64

// ---------------------------------------------------------------------------
// Kernel A: closed-form quantum heads.
//   proj_w = prod_{i=0..w} cos(x_i+theta_i)  (w>=1)
//   proj_0 = prod_{i=1..7} cos(x_i+theta_i)
// Writes projT in [B,H,S,NW] layout so attention K/V loads are contiguous.
// ---------------------------------------------------------------------------
__global__ __launch_bounds__(256) void qproj_kernel(
        const float* __restrict__ x, const float* __restrict__ theta,
        float* __restrict__ projT) {
    int n = blockIdx.x * 256 + threadIdx.x;   // n = (b*S+s)*H + h
    int h  = n & 7;
    int bs = n >> 3;
    int s  = bs & (S_ - 1);
    int b  = bs >> 10;

    const float4* xp = (const float4*)(x + (size_t)n * NW);
    float4 x0 = xp[0];
    float4 x1 = xp[1];
    float a[8] = {x0.x, x0.y, x0.z, x0.w, x1.x, x1.y, x1.z, x1.w};
    float c[8];
#pragma unroll
    for (int i = 0; i < 8; ++i) c[i] = __cosf(a[i] + theta[i]);

    float e[8];
    e[1] = c[0] * c[1];
#pragma unroll
    for (int w = 2; w < 8; ++w) e[w] = e[w - 1] * c[w];
    float p = c[1];
#pragma unroll
    for (int i = 2; i < 8; ++i) p *= c[i];
    e[0] = p;

    float* op = projT + ((((size_t)b * H_ + h) * S_ + s) * NW);
    ((float4*)op)[0] = make_float4(e[0], e[1], e[2], e[3]);
    ((float4*)op)[1] = make_float4(e[4], e[5], e[6], e[7]);
}

// ---------------------------------------------------------------------------
// Kernel B: self-attention per (b,h). Q=K=V=projT[bh]. d_k=8, S=1024.
// Grid (64, 4): block = (bh, q-tile of 256 rows), 256 threads = 1 row each.
// Full K/V tile (32 KB) staged in LDS; all lanes read the same key row per
// iteration -> LDS broadcast, no bank conflicts.
// Softmax uses a FIXED shift: |score| <= 8/sqrt(8) = 2*sqrt(2), and any
// constant shift cancels exactly in softmax, so no online max is needed.
// ---------------------------------------------------------------------------
__global__ __launch_bounds__(256) void attn_kernel(
        const float* __restrict__ projT, float* __restrict__ attnout) {
    __shared__ float kv[S_ * NW];           // 32 KB
    int bh = blockIdx.x;
    int qt = blockIdx.y;
    const float* base = projT + (size_t)bh * (S_ * NW);

    for (int i = threadIdx.x; i < (S_ * NW) / 4; i += 256) {
        ((float4*)kv)[i] = ((const float4*)base)[i];
    }
    __syncthreads();

    int row = qt * 256 + threadIdx.x;
    const float inv_s8 = 0.35355339059327373f;   // 1/sqrt(8)
    float q[8];
#pragma unroll
    for (int i = 0; i < 8; ++i) q[i] = kv[row * NW + i] * inv_s8;

    float o[8] = {0, 0, 0, 0, 0, 0, 0, 0};
    float l = 0.0f;
    const float SHIFT = 2.8284271247461903f;     // 2*sqrt(2) = max possible score

#pragma unroll 4
    for (int j = 0; j < S_; ++j) {
        const float4* kp = (const float4*)(kv + j * NW);
        float4 k0 = kp[0];
        float4 k1 = kp[1];
        float sc = q[0] * k0.x + q[1] * k0.y + q[2] * k0.z + q[3] * k0.w
                 + q[4] * k1.x + q[5] * k1.y + q[6] * k1.z + q[7] * k1.w;
        float w = __expf(sc - SHIFT);
        l += w;
        o[0] += w * k0.x; o[1] += w * k0.y; o[2] += w * k0.z; o[3] += w * k0.w;
        o[4] += w * k1.x; o[5] += w * k1.y; o[6] += w * k1.z; o[7] += w * k1.w;
    }

    float inv_l = 1.0f / l;
    float* op = attnout + (size_t)bh * (S_ * NW) + (size_t)row * NW;
    ((float4*)op)[0] = make_float4(o[0] * inv_l, o[1] * inv_l, o[2] * inv_l, o[3] * inv_l);
    ((float4*)op)[1] = make_float4(o[4] * inv_l, o[5] * inv_l, o[6] * inv_l, o[7] * inv_l);
}

// ---------------------------------------------------------------------------
// Kernel C: out[r,e] = sum_k A[r,k] * W[e,k],  A[r, h*8+w] = attnout[b,h,s,w].
// W staged transposed in LDS with stride 65 (conflict-free: lanes read
// consecutive e -> consecutive banks). 16 rows per block, 4 rows per thread.
// ---------------------------------------------------------------------------
#define CROWS 16
__global__ __launch_bounds__(256) void combine_kernel(
        const float* __restrict__ attnout, const float* __restrict__ W,
        float* __restrict__ out) {
    __shared__ float wl[E_ * 65];           // wl[k*65+e] = W[e,k]
    __shared__ float al[CROWS][E_];
    int r0 = blockIdx.x * CROWS;

    for (int idx = threadIdx.x; idx < E_ * E_; idx += 256) {
        int e = idx >> 6, k = idx & 63;
        wl[k * 65 + e] = W[idx];
    }
    for (int idx = threadIdx.x; idx < CROWS * E_; idx += 256) {
        int lr = idx >> 6, k = idx & 63;
        int r = r0 + lr;
        int b = r >> 10, s = r & (S_ - 1);
        int h = k >> 3,  w = k & 7;
        al[lr][k] = attnout[(((size_t)b * H_ + h) * S_ + s) * NW + w];
    }
    __syncthreads();

    int e = threadIdx.x & 63;
    int g = threadIdx.x >> 6;               // row group 0..3
    float acc[4] = {0, 0, 0, 0};
    for (int k = 0; k < E_; ++k) {
        float wv = wl[k * 65 + e];
#pragma unroll
        for (int j = 0; j < 4; ++j) acc[j] += al[g * 4 + j][k] * wv;
    }
#pragma unroll
    for (int j = 0; j < 4; ++j) {
        int r = r0 + g * 4 + j;
        out[(size_t)r * E_ + e] = acc[j];
    }
}

// ---------------------------------------------------------------------------
extern "C" void kernel_launch(void* const* d_in, const int* in_sizes, int n_in,
                              void* d_out, int out_size, void* d_ws, size_t ws_size,
                              hipStream_t stream) {
    const float* x     = (const float*)d_in[0];   // [B,S,E] = [8,1024,64]
    const float* theta = (const float*)d_in[1];   // [8]
    const float* W     = (const float*)d_in[2];   // [64,64]
    float* out = (float*)d_out;                   // [8,1024,64]

    float* projT   = (float*)d_ws;                // [B,H,S,8] : 2 MB
    float* attnout = projT + (size_t)NTH * NW;    // [B,H,S,8] : 2 MB

    qproj_kernel<<<NTH / 256, 256, 0, stream>>>(x, theta, projT);
    attn_kernel<<<dim3(BH, S_ / 256), 256, 0, stream>>>(projT, attnout);
    combine_kernel<<<NROW / CROWS, 256, 0, stream>>>(attnout, W, out);
}

// Round 2
// 105.195 us; speedup vs baseline: 1.1069x; 1.1069x over previous
//
#include <hip/hip_runtime.h>

#define NW 8
#define S_ 1024
#define H_ 8
#define B_ 8
#define BH 64           // B*H
#define NROW 8192       // B*S
#define E_ 64

// ---------------------------------------------------------------------------
// Fused quantum-proj + self-attention per (b,h).
// Closed form for the 8-qubit circuit (RX product state + CNOT-ring = XOR):
//   proj_w = prod_{i=0..w} cos(x_i+theta_i)  (w>=1);  proj_0 = prod_{i=1..7}.
// Block = (bh, q-tile of 64 rows), 256 threads: 4 threads per Q-row, thread
// p in 0..3 handles keys j = 4*i+p (interleaved -> the wave's 4 distinct
// float4 LDS addresses land in disjoint bank groups; same-p lanes broadcast).
// Partial (o[8], l) reduced across p with __shfl_xor(1,2).
// Fixed softmax shift 2*sqrt(2) (provable max |score|) -> exact, no max pass.
// 1024 blocks -> 4 blocks/CU (128KB LDS), 16 waves/CU.
// ---------------------------------------------------------------------------
__global__ __launch_bounds__(256, 4) void attn_kernel(
        const float* __restrict__ x, const float* __restrict__ theta,
        float* __restrict__ attnout) {
    __shared__ float kv[S_ * NW];           // 32 KB, rows of proj for this bh
    int bh = blockIdx.x;
    int qt = blockIdx.y;
    int b = bh >> 3, h = bh & 7;

    float th[8];
#pragma unroll
    for (int i = 0; i < 8; ++i) th[i] = theta[i];

    // ---- stage: closed-form quantum heads straight from x ----
    for (int s = threadIdx.x; s < S_; s += 256) {
        const float4* xp = (const float4*)(x + ((size_t)((b << 10) + s) << 6) + (h << 3));
        float4 x0 = xp[0];
        float4 x1 = xp[1];
        float c0 = __cosf(x0.x + th[0]);
        float c1 = __cosf(x0.y + th[1]);
        float c2 = __cosf(x0.z + th[2]);
        float c3 = __cosf(x0.w + th[3]);
        float c4 = __cosf(x1.x + th[4]);
        float c5 = __cosf(x1.y + th[5]);
        float c6 = __cosf(x1.z + th[6]);
        float c7 = __cosf(x1.w + th[7]);
        float e1 = c0 * c1;
        float e2 = e1 * c2;
        float e3 = e2 * c3;
        float e4 = e3 * c4;
        float e5 = e4 * c5;
        float e6 = e5 * c6;
        float e7 = e6 * c7;
        float e0 = ((c1 * c2) * (c3 * c4)) * ((c5 * c6) * c7);
        float4* kp = (float4*)(kv + s * NW);
        kp[0] = make_float4(e0, e1, e2, e3);
        kp[1] = make_float4(e4, e5, e6, e7);
    }
    __syncthreads();

    // ---- attention: 4 threads per row ----
    int r = threadIdx.x >> 2;               // 0..63 row within q-tile
    int p = threadIdx.x & 3;                // key-partition
    int row = qt * 64 + r;

    const float inv_s8 = 0.35355339059327373f;   // 1/sqrt(8)
    float q[8];
#pragma unroll
    for (int i = 0; i < 8; ++i) q[i] = kv[row * NW + i] * inv_s8;

    float o[8] = {0, 0, 0, 0, 0, 0, 0, 0};
    float l = 0.0f;
    const float SHIFT = 2.8284271247461903f;     // 2*sqrt(2): max possible score

#pragma unroll 4
    for (int i = 0; i < S_ / 4; ++i) {
        int j = (i << 2) | p;
        const float4* kp = (const float4*)(kv + j * NW);
        float4 k0 = kp[0];
        float4 k1 = kp[1];
        float sc = q[0] * k0.x + q[1] * k0.y + q[2] * k0.z + q[3] * k0.w
                 + q[4] * k1.x + q[5] * k1.y + q[6] * k1.z + q[7] * k1.w;
        float w = __expf(sc - SHIFT);
        l += w;
        o[0] += w * k0.x; o[1] += w * k0.y; o[2] += w * k0.z; o[3] += w * k0.w;
        o[4] += w * k1.x; o[5] += w * k1.y; o[6] += w * k1.z; o[7] += w * k1.w;
    }

    // reduce partials across the 4 key-partitions (lanes differ in low 2 bits)
#pragma unroll
    for (int m = 1; m <= 2; m <<= 1) {
#pragma unroll
        for (int i = 0; i < 8; ++i) o[i] += __shfl_xor(o[i], m, 64);
        l += __shfl_xor(l, m, 64);
    }

    if (p < 2) {
        float inv_l = 1.0f / l;
        float4 v = (p == 0)
            ? make_float4(o[0] * inv_l, o[1] * inv_l, o[2] * inv_l, o[3] * inv_l)
            : make_float4(o[4] * inv_l, o[5] * inv_l, o[6] * inv_l, o[7] * inv_l);
        // write in [B,S,E] layout so combine reads coalesced
        *(float4*)(attnout + ((size_t)((b << 10) + row) << 6) + (h << 3) + (p << 2)) = v;
    }
}

// ---------------------------------------------------------------------------
// combine: out[r,e] = sum_k A[r,k] * W[e,k];  A is [8192,64] row-major now.
// W staged transposed in LDS stride-65 (conflict-free). 16 rows/block,
// 4 rows/thread register blocking.
// ---------------------------------------------------------------------------
#define CROWS 16
__global__ __launch_bounds__(256) void combine_kernel(
        const float* __restrict__ A, const float* __restrict__ W,
        float* __restrict__ out) {
    __shared__ float wl[E_ * 65];           // wl[k*65+e] = W[e,k]
    __shared__ float al[CROWS][E_];
    int r0 = blockIdx.x * CROWS;

    for (int idx = threadIdx.x; idx < E_ * E_; idx += 256) {
        int e = idx >> 6, k = idx & 63;
        wl[k * 65 + e] = W[idx];
    }
    // coalesced float4 row staging: exactly 1 float4 per thread
    ((float4*)al)[threadIdx.x] = ((const float4*)(A + (size_t)r0 * E_))[threadIdx.x];
    __syncthreads();

    int e = threadIdx.x & 63;
    int g = threadIdx.x >> 6;               // wave id = row group 0..3
    float acc[4] = {0, 0, 0, 0};
    for (int k = 0; k < E_; ++k) {
        float wv = wl[k * 65 + e];
#pragma unroll
        for (int j = 0; j < 4; ++j) acc[j] += al[g * 4 + j][k] * wv;
    }
#pragma unroll
    for (int j = 0; j < 4; ++j) {
        int r = r0 + g * 4 + j;
        out[(size_t)r * E_ + e] = acc[j];
    }
}

// ---------------------------------------------------------------------------
extern "C" void kernel_launch(void* const* d_in, const int* in_sizes, int n_in,
                              void* d_out, int out_size, void* d_ws, size_t ws_size,
                              hipStream_t stream) {
    const float* x     = (const float*)d_in[0];   // [8,1024,64] fp32
    const float* theta = (const float*)d_in[1];   // [8]
    const float* W     = (const float*)d_in[2];   // [64,64]
    float* out = (float*)d_out;                   // [8,1024,64]

    float* attnout = (float*)d_ws;                // [B,S,E] : 2 MB

    attn_kernel<<<dim3(BH, S_ / 64), 256, 0, stream>>>(x, theta, attnout);
    combine_kernel<<<NROW / CROWS, 256, 0, stream>>>(attnout, W, out);
}

// Round 4
// 87.537 us; speedup vs baseline: 1.3301x; 1.2017x over previous
//
#include <hip/hip_runtime.h>

typedef _Float16 half4v __attribute__((ext_vector_type(4)));
typedef float float4v __attribute__((ext_vector_type(4)));

#define NW 8
#define S_ 1024
#define H_ 8
#define B_ 8
#define BH 64           // B*H
#define NROW 8192       // B*S
#define E_ 64
#define KST 20          // f16 stride per kv row (conflict-free, 8B-aligned)

// ---------------------------------------------------------------------------
// Fused quantum-proj + MFMA flash attention per (b,h).
// Closed form: proj_w = prod_{i=0..w} cos(x_i+th_i) (w>=1); proj_0 = prod_{1..7}.
// Staged as f16 in LDS, row stride 20 f16 (40 B): K-frag ds_read_b64 banks
// 10*row%32 are all-distinct over 16 rows -> <=2-way (free).
//
// mfma1: A=K-tile, B=Q-tile (Q pre-scaled by log2e/sqrt(8)) -> C = S^T in
// C-layout [col=query=lane&15, row=key=quad*4+reg] == A-layout of P for
// mfma2 (m=query=lane&15, k=key=quad*4+reg). No transpose needed.
// P = exp2(S - 4.0804) elementwise (fixed shift: |S|<=4.081, exact in softmax).
// mfma2: B=V' with col 8 = ones -> O cols 0..7, row-sum l in col 8.
// kvh[8..15] (row-0 tail, unused by stride-20 rows) holds {1,0,...}: serves
// both the V' constant columns and the zero region for d>=8 fragment lanes.
// ---------------------------------------------------------------------------
__global__ __launch_bounds__(256, 4) void attn_kernel(
        const float* __restrict__ x, const float* __restrict__ theta,
        float* __restrict__ attnout) {
    __shared__ _Float16 kvh[S_ * KST];      // 40960 B -> 4 blocks/CU
    int bh = blockIdx.x;
    int b = bh >> 3, h = bh & 7;
    int tid = threadIdx.x;

    float th[8];
#pragma unroll
    for (int i = 0; i < 8; ++i) th[i] = theta[i];

    if (tid < 8) kvh[8 + tid] = (tid == 0) ? (_Float16)1.0f : (_Float16)0.0f;

    // ---- stage: closed-form quantum heads -> f16 LDS ----
    for (int s = tid; s < S_; s += 256) {
        const float4* xp = (const float4*)(x + (((size_t)(b << 10) + s) << 6) + (h << 3));
        float4 x0 = xp[0];
        float4 x1 = xp[1];
        float c0 = __cosf(x0.x + th[0]);
        float c1 = __cosf(x0.y + th[1]);
        float c2 = __cosf(x0.z + th[2]);
        float c3 = __cosf(x0.w + th[3]);
        float c4 = __cosf(x1.x + th[4]);
        float c5 = __cosf(x1.y + th[5]);
        float c6 = __cosf(x1.z + th[6]);
        float c7 = __cosf(x1.w + th[7]);
        float e1 = c0 * c1;
        float e2 = e1 * c2;
        float e3 = e2 * c3;
        float e4 = e3 * c4;
        float e5 = e4 * c5;
        float e6 = e5 * c6;
        float e7 = e6 * c7;
        float e0 = ((c1 * c2) * (c3 * c4)) * ((c5 * c6) * c7);
        half4v lo = {(_Float16)e0, (_Float16)e1, (_Float16)e2, (_Float16)e3};
        half4v hi = {(_Float16)e4, (_Float16)e5, (_Float16)e6, (_Float16)e7};
        *(half4v*)&kvh[s * KST]     = lo;
        *(half4v*)&kvh[s * KST + 4] = hi;
    }
    __syncthreads();

    int lane = tid & 63;
    int wv   = tid >> 6;                    // wave 0..3 -> its own 16-row q-tile
    int col  = lane & 15;
    int quad = lane >> 4;
    int q0   = blockIdx.y * 64 + wv * 16;

    // Q-frag: B[k=d][n=query]: lane holds Q[query=col][d=quad*4+r], d>=8 -> 0
    int qidx = (quad < 2) ? ((q0 + col) * KST + quad * 4) : 12;
    half4v qf = *(const half4v*)&kvh[qidx];
    qf *= (_Float16)0.51012921f;            // log2(e)/sqrt(8)

    // K-frag: A[m=key][k=d]: lane holds K[key=col][d=quad*4+r], d>=8 -> 0
    int kaddr = (quad < 2) ? (col * KST + quad * 4) : 12;
    int kstep = (quad < 2) ? (16 * KST) : 0;

    // V'-frag: B[k=key][n=col]: lane holds V'[key=quad*4+r][n=col]
    //   col<8: V rows from kvh; col>=8: constants kvh[col] (1.0 at col 8)
    int va    = (col < 8) ? (quad * 4 * KST + col) : col;
    int vstep = (col < 8) ? (16 * KST) : 0;
    int vr    = (col < 8) ? KST : 0;

    float4v oacc = {0.f, 0.f, 0.f, 0.f};
    const float4v zc = {0.f, 0.f, 0.f, 0.f};
    const float SH = 4.08040428f;           // 2*sqrt(2)*log2(e)

    for (int kt = 0; kt < 64; ++kt) {
        half4v kf = *(const half4v*)&kvh[kaddr];
        float4v st = __builtin_amdgcn_mfma_f32_16x16x16f16(kf, qf, zc, 0, 0, 0);
        _Float16 p0 = (_Float16)exp2f(st[0] - SH);
        _Float16 p1 = (_Float16)exp2f(st[1] - SH);
        _Float16 p2 = (_Float16)exp2f(st[2] - SH);
        _Float16 p3 = (_Float16)exp2f(st[3] - SH);
        half4v pf = {p0, p1, p2, p3};
        _Float16 v0 = kvh[va];
        _Float16 v1 = kvh[va + vr];
        _Float16 v2 = kvh[va + 2 * vr];
        _Float16 v3 = kvh[va + 3 * vr];
        half4v vf = {v0, v1, v2, v3};
        oacc = __builtin_amdgcn_mfma_f32_16x16x16f16(pf, vf, oacc, 0, 0, 0);
        kaddr += kstep;
        va += vstep;
    }

    // l[q] sits in column 8, same quad: fetch per reg, normalize, store cols 0..7
    int lsrc = (lane & 48) | 8;
    float l0 = __shfl(oacc[0], lsrc, 64);
    float l1 = __shfl(oacc[1], lsrc, 64);
    float l2 = __shfl(oacc[2], lsrc, 64);
    float l3 = __shfl(oacc[3], lsrc, 64);
    if (col < 8) {
        float* op = attnout + (((size_t)(b << 10) + q0 + quad * 4) << 6) + (h << 3) + col;
        op[0 << 6] = oacc[0] * __builtin_amdgcn_rcpf(l0);
        op[1 << 6] = oacc[1] * __builtin_amdgcn_rcpf(l1);
        op[2 << 6] = oacc[2] * __builtin_amdgcn_rcpf(l2);
        op[3 << 6] = oacc[3] * __builtin_amdgcn_rcpf(l3);
    }
}

// ---------------------------------------------------------------------------
// combine: out[r,e] = sum_k A[r,k] * W[e,k];  A is [8192,64] row-major.
// ---------------------------------------------------------------------------
#define CROWS 16
__global__ __launch_bounds__(256) void combine_kernel(
        const float* __restrict__ A, const float* __restrict__ W,
        float* __restrict__ out) {
    __shared__ float wl[E_ * 65];           // wl[k*65+e] = W[e,k]
    __shared__ float al[CROWS][E_];
    int r0 = blockIdx.x * CROWS;

    for (int idx = threadIdx.x; idx < E_ * E_; idx += 256) {
        int e = idx >> 6, k = idx & 63;
        wl[k * 65 + e] = W[idx];
    }
    ((float4*)al)[threadIdx.x] = ((const float4*)(A + (size_t)r0 * E_))[threadIdx.x];
    __syncthreads();

    int e = threadIdx.x & 63;
    int g = threadIdx.x >> 6;
    float acc[4] = {0, 0, 0, 0};
    for (int k = 0; k < E_; ++k) {
        float wv = wl[k * 65 + e];
#pragma unroll
        for (int j = 0; j < 4; ++j) acc[j] += al[g * 4 + j][k] * wv;
    }
#pragma unroll
    for (int j = 0; j < 4; ++j) {
        int r = r0 + g * 4 + j;
        out[(size_t)r * E_ + e] = acc[j];
    }
}

// ---------------------------------------------------------------------------
extern "C" void kernel_launch(void* const* d_in, const int* in_sizes, int n_in,
                              void* d_out, int out_size, void* d_ws, size_t ws_size,
                              hipStream_t stream) {
    const float* x     = (const float*)d_in[0];   // [8,1024,64] fp32
    const float* theta = (const float*)d_in[1];   // [8]
    const float* W     = (const float*)d_in[2];   // [64,64]
    float* out = (float*)d_out;                   // [8,1024,64]

    float* attnout = (float*)d_ws;                // [B,S,E] fp32 : 2 MB

    attn_kernel<<<dim3(BH, S_ / 64), 256, 0, stream>>>(x, theta, attnout);
    combine_kernel<<<NROW / CROWS, 256, 0, stream>>>(attnout, W, out);
}

// Round 5
// 84.526 us; speedup vs baseline: 1.3775x; 1.0356x over previous
//
#include <hip/hip_runtime.h>

typedef _Float16 half4v __attribute__((ext_vector_type(4)));
typedef float float4v __attribute__((ext_vector_type(4)));

#define NW 8
#define S_ 1024
#define H_ 8
#define B_ 8
#define BH 64           // B*H
#define NROW 8192       // B*S
#define E_ 64
#define KST 20          // f16 stride per kv row (conflict-free-ish, 8B-aligned)
#define VST 1032        // vT row stride in halves (2064 B, 8B-aligned)

// ---------------------------------------------------------------------------
// Fused quantum-proj + MFMA flash attention per (b,h).
// Closed form: proj_w = prod_{i=0..w} cos(x_i+th_i) (w>=1); proj_0 = prod_{1..7}.
//
// Per wave: TWO 16-query tiles (32 queries) sharing the same K/V fragments.
// mfma1: A=K-tile, B=Q-tile (Q pre-scaled log2e/sqrt(8)) -> S^T in C-layout
//   [col=query, row=key] == A-layout of P for mfma2. No transpose.
// P = exp2(S - 4.0804) (fixed shift, exact in softmax; |S| <= 4.081).
// mfma2: B = V' read from a TRANSPOSED LDS copy vT[d][key]:
//   rows 0..7 = V^T, row 8 = ones (gives row-sum l in col 8), rows 9..15 = 0.
//   -> single ds_read_b64 per iter for the whole wave, branchless.
// kf/vf prefetched one iteration ahead (rotation) so LDS latency overlaps
// the exp chain.
// LDS 74 KB -> 2 blocks/CU; grid (64,8)=512 blocks = exactly 2/CU.
// ---------------------------------------------------------------------------
__global__ __launch_bounds__(256, 2) void attn_kernel(
        const float* __restrict__ x, const float* __restrict__ theta,
        float* __restrict__ attnout) {
    __shared__ _Float16 kvh[S_ * KST];      // 40960 B, row-major proj (K/Q source)
    __shared__ _Float16 vT[16 * VST];       // 33024 B, d-major V + const rows
    int bh = blockIdx.x;
    int b = bh >> 3, h = bh & 7;
    int tid = threadIdx.x;

    float th[8];
#pragma unroll
    for (int i = 0; i < 8; ++i) th[i] = theta[i];

    // constants region in kvh row-0 tail: kvh[8..15] = {1,0,0,0,0,0,0,0}
    // (kvh[12..15] = zeros serve the d>=8 K/Q fragment lanes)
    if (tid < 8) kvh[8 + tid] = (tid == 0) ? (_Float16)1.0f : (_Float16)0.0f;

    // vT constant rows: row 8 = ones, rows 9..15 = zeros (half4v stores)
    {
        const half4v ones  = {(_Float16)1.0f, (_Float16)1.0f, (_Float16)1.0f, (_Float16)1.0f};
        const half4v zeros = {(_Float16)0.0f, (_Float16)0.0f, (_Float16)0.0f, (_Float16)0.0f};
        for (int i = tid; i < 8 * (S_ / 4); i += 256) {
            int d = 8 + (i >> 8);           // 256 half4v chunks per row
            int s4 = (i & 255) << 2;
            *(half4v*)&vT[d * VST + s4] = (d == 8) ? ones : zeros;
        }
    }

    // ---- stage: closed-form quantum heads -> f16 LDS (rows + transposed) ----
    for (int s = tid; s < S_; s += 256) {
        const float4* xp = (const float4*)(x + (((size_t)(b << 10) + s) << 6) + (h << 3));
        float4 x0 = xp[0];
        float4 x1 = xp[1];
        float c0 = __cosf(x0.x + th[0]);
        float c1 = __cosf(x0.y + th[1]);
        float c2 = __cosf(x0.z + th[2]);
        float c3 = __cosf(x0.w + th[3]);
        float c4 = __cosf(x1.x + th[4]);
        float c5 = __cosf(x1.y + th[5]);
        float c6 = __cosf(x1.z + th[6]);
        float c7 = __cosf(x1.w + th[7]);
        float e1 = c0 * c1;
        float e2 = e1 * c2;
        float e3 = e2 * c3;
        float e4 = e3 * c4;
        float e5 = e4 * c5;
        float e6 = e5 * c6;
        float e7 = e6 * c7;
        float e0 = ((c1 * c2) * (c3 * c4)) * ((c5 * c6) * c7);
        _Float16 h0 = (_Float16)e0, h1 = (_Float16)e1, h2 = (_Float16)e2, h3 = (_Float16)e3;
        _Float16 h4 = (_Float16)e4, h5 = (_Float16)e5, h6 = (_Float16)e6, h7 = (_Float16)e7;
        half4v lo = {h0, h1, h2, h3};
        half4v hi = {h4, h5, h6, h7};
        *(half4v*)&kvh[s * KST]     = lo;
        *(half4v*)&kvh[s * KST + 4] = hi;
        vT[0 * VST + s] = h0; vT[1 * VST + s] = h1;
        vT[2 * VST + s] = h2; vT[3 * VST + s] = h3;
        vT[4 * VST + s] = h4; vT[5 * VST + s] = h5;
        vT[6 * VST + s] = h6; vT[7 * VST + s] = h7;
    }
    __syncthreads();

    int lane = tid & 63;
    int wv   = tid >> 6;                    // wave 0..3
    int col  = lane & 15;
    int quad = lane >> 4;
    int q0   = blockIdx.y * 128 + wv * 32;  // 32 queries per wave, 2 tiles

    // Q-frags (B-layout): lane holds Q[query=col][d=quad*4+r]; d>=8 -> zeros
    int qia = (quad < 2) ? ((q0 + col) * KST + quad * 4) : 12;
    int qib = (quad < 2) ? ((q0 + 16 + col) * KST + quad * 4) : 12;
    half4v qfa = *(const half4v*)&kvh[qia];
    half4v qfb = *(const half4v*)&kvh[qib];
    qfa *= (_Float16)0.51012921f;           // log2(e)/sqrt(8)
    qfb *= (_Float16)0.51012921f;

    // K-frag (A-layout): lane holds K[key=kt*16+col][d=quad*4+r]; d>=8 -> zeros
    int kbase = (quad < 2) ? (col * KST + quad * 4) : 12;
    int kstep = (quad < 2) ? (16 * KST) : 0;
    // V'-frag (B-layout): lane holds V'[key=kt*16+quad*4+r][n=col] = vT[col][key]
    int vbase = col * VST + quad * 4;

    float4v oa = {0.f, 0.f, 0.f, 0.f};
    float4v ob = {0.f, 0.f, 0.f, 0.f};
    const float4v zc = {0.f, 0.f, 0.f, 0.f};
    const float SH = 4.08040428f;           // 2*sqrt(2)*log2(e)

    half4v kf = *(const half4v*)&kvh[kbase];
    half4v vf = *(const half4v*)&vT[vbase];

#pragma unroll 2
    for (int kt = 0; kt < 64; ++kt) {
        float4v sa = __builtin_amdgcn_mfma_f32_16x16x16f16(kf, qfa, zc, 0, 0, 0);
        float4v sb = __builtin_amdgcn_mfma_f32_16x16x16f16(kf, qfb, zc, 0, 0, 0);
        int nkt = (kt + 1) & 63;            // wrap -> no branch, safe address
        half4v kfn = *(const half4v*)&kvh[kbase + nkt * kstep];
        half4v vfn = *(const half4v*)&vT[vbase + nkt * 16];
        half4v pa = {(_Float16)exp2f(sa[0] - SH), (_Float16)exp2f(sa[1] - SH),
                     (_Float16)exp2f(sa[2] - SH), (_Float16)exp2f(sa[3] - SH)};
        half4v pb = {(_Float16)exp2f(sb[0] - SH), (_Float16)exp2f(sb[1] - SH),
                     (_Float16)exp2f(sb[2] - SH), (_Float16)exp2f(sb[3] - SH)};
        oa = __builtin_amdgcn_mfma_f32_16x16x16f16(pa, vf, oa, 0, 0, 0);
        ob = __builtin_amdgcn_mfma_f32_16x16x16f16(pb, vf, ob, 0, 0, 0);
        kf = kfn;
        vf = vfn;
    }

    // l[q] sits in column 8 (ones row of vT), same quad: shfl per reg.
    int lsrc = (lane & 48) | 8;
    {
        float l0 = __shfl(oa[0], lsrc, 64);
        float l1 = __shfl(oa[1], lsrc, 64);
        float l2 = __shfl(oa[2], lsrc, 64);
        float l3 = __shfl(oa[3], lsrc, 64);
        if (col < 8) {
            float* op = attnout + (((size_t)(b << 10) + q0 + quad * 4) << 6) + (h << 3) + col;
            op[0 << 6] = oa[0] * __builtin_amdgcn_rcpf(l0);
            op[1 << 6] = oa[1] * __builtin_amdgcn_rcpf(l1);
            op[2 << 6] = oa[2] * __builtin_amdgcn_rcpf(l2);
            op[3 << 6] = oa[3] * __builtin_amdgcn_rcpf(l3);
        }
    }
    {
        float l0 = __shfl(ob[0], lsrc, 64);
        float l1 = __shfl(ob[1], lsrc, 64);
        float l2 = __shfl(ob[2], lsrc, 64);
        float l3 = __shfl(ob[3], lsrc, 64);
        if (col < 8) {
            float* op = attnout + (((size_t)(b << 10) + q0 + 16 + quad * 4) << 6) + (h << 3) + col;
            op[0 << 6] = ob[0] * __builtin_amdgcn_rcpf(l0);
            op[1 << 6] = ob[1] * __builtin_amdgcn_rcpf(l1);
            op[2 << 6] = ob[2] * __builtin_amdgcn_rcpf(l2);
            op[3 << 6] = ob[3] * __builtin_amdgcn_rcpf(l3);
        }
    }
}

// ---------------------------------------------------------------------------
// combine: out[r,e] = sum_k A[r,k] * W[e,k];  A is [8192,64] row-major.
// ---------------------------------------------------------------------------
#define CROWS 16
__global__ __launch_bounds__(256) void combine_kernel(
        const float* __restrict__ A, const float* __restrict__ W,
        float* __restrict__ out) {
    __shared__ float wl[E_ * 65];           // wl[k*65+e] = W[e,k]
    __shared__ float al[CROWS][E_];
    int r0 = blockIdx.x * CROWS;

    for (int idx = threadIdx.x; idx < E_ * E_; idx += 256) {
        int e = idx >> 6, k = idx & 63;
        wl[k * 65 + e] = W[idx];
    }
    ((float4*)al)[threadIdx.x] = ((const float4*)(A + (size_t)r0 * E_))[threadIdx.x];
    __syncthreads();

    int e = threadIdx.x & 63;
    int g = threadIdx.x >> 6;
    float acc[4] = {0, 0, 0, 0};
    for (int k = 0; k < E_; ++k) {
        float wv = wl[k * 65 + e];
#pragma unroll
        for (int j = 0; j < 4; ++j) acc[j] += al[g * 4 + j][k] * wv;
    }
#pragma unroll
    for (int j = 0; j < 4; ++j) {
        int r = r0 + g * 4 + j;
        out[(size_t)r * E_ + e] = acc[j];
    }
}

// ---------------------------------------------------------------------------
extern "C" void kernel_launch(void* const* d_in, const int* in_sizes, int n_in,
                              void* d_out, int out_size, void* d_ws, size_t ws_size,
                              hipStream_t stream) {
    const float* x     = (const float*)d_in[0];   // [8,1024,64] fp32
    const float* theta = (const float*)d_in[1];   // [8]
    const float* W     = (const float*)d_in[2];   // [64,64]
    float* out = (float*)d_out;                   // [8,1024,64]

    float* attnout = (float*)d_ws;                // [B,S,E] fp32 : 2 MB

    attn_kernel<<<dim3(BH, S_ / 128), 256, 0, stream>>>(x, theta, attnout);
    combine_kernel<<<NROW / CROWS, 256, 0, stream>>>(attnout, W, out);
}

// Round 7
// 80.745 us; speedup vs baseline: 1.4420x; 1.0468x over previous
//
#include <hip/hip_runtime.h>

typedef _Float16 half4v __attribute__((ext_vector_type(4)));
typedef __fp16 fp16x2 __attribute__((ext_vector_type(2)));
typedef float float4v __attribute__((ext_vector_type(4)));

#define NW 8
#define S_ 1024
#define H_ 8
#define B_ 8
#define BH 64           // B*H
#define NROW 8192       // B*S
#define E_ 64
#define VST 1032        // vT row stride in halves (2064 B, 8 B aligned)
#define ZOFF (9 * VST)  // 16-half zero region
#define NLDS (9 * VST + 16)   // 18608 B total LDS

// Pack 4 floats -> half4v via v_cvt_pkrtz_f16_f32 (2 instrs, round-to-zero).
static __device__ inline half4v pack4(float a, float b, float c, float d) {
    union { fp16x2 f2[2]; half4v h4; } u;
    u.f2[0] = __builtin_amdgcn_cvt_pkrtz(a, b);
    u.f2[1] = __builtin_amdgcn_cvt_pkrtz(c, d);
    return u.h4;
}

// ---------------------------------------------------------------------------
// Fused quantum-proj + MFMA flash attention per (b,h), O^T formulation.
// Closed form: proj_w = prod_{i=0..w} cos(x_i+th_i) (w>=1); proj_0 = prod_{1..7}.
//
// Single LDS buffer vT[d][s]: rows 0..7 = proj^T, row 8 = ones, plus a
// 16-half zero region at ZOFF. All fragments come from vT:
//   K-frag (A of mfma1): K[key=col][d=quad*4+j]   = vT[d][key]   (4x u16)
//   Q-frag (B of mfma1): Q[q=col][d=quad*4+j]     = vT[d][q]     (setup only)
//   V'^T-frag (A of mfma2): V'[key=quad*4+j][col] = vT[col][key] (1x b64)
// mfma1 C-layout [row=key, col=q] == B=P^T layout of mfma2 after exp ->
// no data movement between the two MFMAs. mfma2 computes O^T = V'^T P^T:
// C row = d (quad*4+reg), col = q -> each quad<2 lane stores one float4 of
// output; l[q] = ones-row result sits in lane 32|q reg 0 (row 8).
// P = exp2(S-4.0804), fixed shift exact in softmax (|S|<=4.081).
// d>=8 / col>=9 fragment lanes read the zero region (branchless base+step).
// K/V frags prefetched at depth 2 (rotation, unroll 2) to hide LDS latency.
// LDS 18.6 KB; grid (64,16)=1024 blocks = 4 blocks/CU, 16 waves/CU.
// ---------------------------------------------------------------------------
__global__ __launch_bounds__(256, 4) void attn_kernel(
        const float* __restrict__ x, const float* __restrict__ theta,
        float* __restrict__ attnout) {
    __shared__ _Float16 vT[NLDS];
    int bh = blockIdx.x;
    int b = bh >> 3, h = bh & 7;
    int tid = threadIdx.x;

    float th[8];
#pragma unroll
    for (int i = 0; i < 8; ++i) th[i] = theta[i];

    // zero region (16 halves) and ones row (1024 halves)
    {
        const half4v zer = {(_Float16)0.f, (_Float16)0.f, (_Float16)0.f, (_Float16)0.f};
        const half4v one = {(_Float16)1.f, (_Float16)1.f, (_Float16)1.f, (_Float16)1.f};
        if (tid < 4) *(half4v*)&vT[ZOFF + tid * 4] = zer;
        *(half4v*)&vT[8 * VST + tid * 4] = one;     // 256 threads x 4 = 1024
    }

    // ---- stage: closed-form quantum heads -> transposed f16 LDS ----
    for (int s = tid; s < S_; s += 256) {
        const float4* xp = (const float4*)(x + (((size_t)(b << 10) + s) << 6) + (h << 3));
        float4 x0 = xp[0];
        float4 x1 = xp[1];
        float c0 = __cosf(x0.x + th[0]);
        float c1 = __cosf(x0.y + th[1]);
        float c2 = __cosf(x0.z + th[2]);
        float c3 = __cosf(x0.w + th[3]);
        float c4 = __cosf(x1.x + th[4]);
        float c5 = __cosf(x1.y + th[5]);
        float c6 = __cosf(x1.z + th[6]);
        float c7 = __cosf(x1.w + th[7]);
        float e1 = c0 * c1;
        float e2 = e1 * c2;
        float e3 = e2 * c3;
        float e4 = e3 * c4;
        float e5 = e4 * c5;
        float e6 = e5 * c6;
        float e7 = e6 * c7;
        float e0 = ((c1 * c2) * (c3 * c4)) * ((c5 * c6) * c7);
        vT[0 * VST + s] = (_Float16)e0;
        vT[1 * VST + s] = (_Float16)e1;
        vT[2 * VST + s] = (_Float16)e2;
        vT[3 * VST + s] = (_Float16)e3;
        vT[4 * VST + s] = (_Float16)e4;
        vT[5 * VST + s] = (_Float16)e5;
        vT[6 * VST + s] = (_Float16)e6;
        vT[7 * VST + s] = (_Float16)e7;
    }
    __syncthreads();

    int lane = tid & 63;
    int wv   = tid >> 6;
    int col  = lane & 15;
    int quad = lane >> 4;
    int q0   = blockIdx.y * 64 + wv * 16;   // 16 queries per wave

    bool lo2 = (quad < 2);

    // Q-frag (B-layout): Q[q=q0+col][d=quad*4+j]; d>=8 -> zeros
    half4v qf;
    {
        int d0 = quad * 4;
        int a0 = lo2 ? ((d0 + 0) * VST + q0 + col) : (ZOFF + 0);
        int a1 = lo2 ? ((d0 + 1) * VST + q0 + col) : (ZOFF + 1);
        int a2 = lo2 ? ((d0 + 2) * VST + q0 + col) : (ZOFF + 2);
        int a3 = lo2 ? ((d0 + 3) * VST + q0 + col) : (ZOFF + 3);
        half4v t = {vT[a0], vT[a1], vT[a2], vT[a3]};
        qf = t * (_Float16)0.51012921f;     // log2(e)/sqrt(8)
    }

    // K-frag addressing: addr_j(kt) = rb_j + cbase + kt*cstep
    int rb0 = lo2 ? ((quad * 4 + 0) * VST) : (ZOFF + 0);
    int rb1 = lo2 ? ((quad * 4 + 1) * VST) : (ZOFF + 1);
    int rb2 = lo2 ? ((quad * 4 + 2) * VST) : (ZOFF + 2);
    int rb3 = lo2 ? ((quad * 4 + 3) * VST) : (ZOFF + 3);
    int cbase = lo2 ? col : 0;
    int cstep = lo2 ? 16 : 0;

    // V'^T-frag addressing: addr(kt) = vbase + quad*4 + kt*vstep (b64)
    int vbase = (col < 9) ? (col * VST) : ZOFF;
    int vstep = (col < 9) ? 16 : 0;

#define LOADK(dst, t) { int c_ = cbase + (t) * cstep; \
        half4v r_ = {vT[rb0 + c_], vT[rb1 + c_], vT[rb2 + c_], vT[rb3 + c_]}; dst = r_; }
#define LOADV(dst, t) { dst = *(const half4v*)&vT[vbase + quad * 4 + (t) * vstep]; }

    float4v oacc = {0.f, 0.f, 0.f, 0.f};
    const float4v zc = {0.f, 0.f, 0.f, 0.f};
    const float SH = 4.08040428f;           // 2*sqrt(2)*log2(e)

    half4v kA, vA, kB, vB, kN, vN, kM, vM;
    LOADK(kA, 0); LOADV(vA, 0);
    LOADK(kB, 1); LOADV(vB, 1);

    for (int kt = 0; kt < 64; kt += 2) {
        // --- iter kt ---
        float4v s0 = __builtin_amdgcn_mfma_f32_16x16x16f16(kA, qf, zc, 0, 0, 0);
        int t2 = (kt + 2) & 63;
        LOADK(kN, t2); LOADV(vN, t2);
        float p0 = __builtin_amdgcn_exp2f(s0[0] - SH);
        float p1 = __builtin_amdgcn_exp2f(s0[1] - SH);
        float p2 = __builtin_amdgcn_exp2f(s0[2] - SH);
        float p3 = __builtin_amdgcn_exp2f(s0[3] - SH);
        half4v pa = pack4(p0, p1, p2, p3);
        oacc = __builtin_amdgcn_mfma_f32_16x16x16f16(vA, pa, oacc, 0, 0, 0);
        // --- iter kt+1 ---
        float4v s1 = __builtin_amdgcn_mfma_f32_16x16x16f16(kB, qf, zc, 0, 0, 0);
        int t3 = (kt + 3) & 63;
        LOADK(kM, t3); LOADV(vM, t3);
        float r0 = __builtin_amdgcn_exp2f(s1[0] - SH);
        float r1 = __builtin_amdgcn_exp2f(s1[1] - SH);
        float r2 = __builtin_amdgcn_exp2f(s1[2] - SH);
        float r3 = __builtin_amdgcn_exp2f(s1[3] - SH);
        half4v pb = pack4(r0, r1, r2, r3);
        oacc = __builtin_amdgcn_mfma_f32_16x16x16f16(vB, pb, oacc, 0, 0, 0);
        // rotate
        kA = kN; vA = vN; kB = kM; vB = vM;
    }

    // l[q] = ones-row (row 8 of O^T) = lane 32|q, reg 0
    float l = __shfl(oacc[0], 32 | col, 64);
    if (lo2) {
        float inv = __builtin_amdgcn_rcpf(l);
        float4 ov = make_float4(oacc[0] * inv, oacc[1] * inv, oacc[2] * inv, oacc[3] * inv);
        // O^T C-layout: lane holds O[q=col][d=quad*4 .. +3] -> one float4 store
        *(float4*)(attnout + (((size_t)(b << 10) + q0 + col) << 6) + (h << 3) + quad * 4) = ov;
    }
#undef LOADK
#undef LOADV
}

// ---------------------------------------------------------------------------
// combine: out[r,e] = sum_k A[r,k] * W[e,k];  A is [8192,64] row-major.
// ---------------------------------------------------------------------------
#define CROWS 16
__global__ __launch_bounds__(256) void combine_kernel(
        const float* __restrict__ A, const float* __restrict__ W,
        float* __restrict__ out) {
    __shared__ float wl[E_ * 65];           // wl[k*65+e] = W[e,k]
    __shared__ float al[CROWS][E_];
    int r0 = blockIdx.x * CROWS;

    for (int idx = threadIdx.x; idx < E_ * E_; idx += 256) {
        int e = idx >> 6, k = idx & 63;
        wl[k * 65 + e] = W[idx];
    }
    ((float4*)al)[threadIdx.x] = ((const float4*)(A + (size_t)r0 * E_))[threadIdx.x];
    __syncthreads();

    int e = threadIdx.x & 63;
    int g = threadIdx.x >> 6;
    float acc[4] = {0, 0, 0, 0};
    for (int k = 0; k < E_; ++k) {
        float wv = wl[k * 65 + e];
#pragma unroll
        for (int j = 0; j < 4; ++j) acc[j] += al[g * 4 + j][k] * wv;
    }
#pragma unroll
    for (int j = 0; j < 4; ++j) {
        int r = r0 + g * 4 + j;
        out[(size_t)r * E_ + e] = acc[j];
    }
}

// ---------------------------------------------------------------------------
extern "C" void kernel_launch(void* const* d_in, const int* in_sizes, int n_in,
                              void* d_out, int out_size, void* d_ws, size_t ws_size,
                              hipStream_t stream) {
    const float* x     = (const float*)d_in[0];   // [8,1024,64] fp32
    const float* theta = (const float*)d_in[1];   // [8]
    const float* W     = (const float*)d_in[2];   // [64,64]
    float* out = (float*)d_out;                   // [8,1024,64]

    float* attnout = (float*)d_ws;                // [B,S,E] fp32 : 2 MB

    attn_kernel<<<dim3(BH, S_ / 64), 256, 0, stream>>>(x, theta, attnout);
    combine_kernel<<<NROW / CROWS, 256, 0, stream>>>(attnout, W, out);
}

// Round 8
// 74.199 us; speedup vs baseline: 1.5693x; 1.0882x over previous
//
#include <hip/hip_runtime.h>

typedef _Float16 half4v __attribute__((ext_vector_type(4)));
typedef __fp16 fp16x2 __attribute__((ext_vector_type(2)));
typedef float float4v __attribute__((ext_vector_type(4)));

#define S_ 1024
#define H_ 8
#define B_ 8
#define BH 64           // B*H
#define NROW 8192       // B*S
#define E_ 64

#define VST 1032        // vT row stride (halves)
#define VZOFF (9 * VST) // 16-half zero region for vT (V-frag cols 9..15)
#define NV (9 * VST + 16)
#define KFZ (64 * 128)  // kF zero region (8 halves) for lanes 32..63
#define NKF (64 * 128 + 8)

// Pack 4 floats -> half4v via v_cvt_pkrtz_f16_f32.
static __device__ inline half4v pack4(float a, float b, float c, float d) {
    union { fp16x2 f2[2]; half4v h4; } u;
    u.f2[0] = __builtin_amdgcn_cvt_pkrtz(a, b);
    u.f2[1] = __builtin_amdgcn_cvt_pkrtz(c, d);
    return u.h4;
}

// ---------------------------------------------------------------------------
// Fused quantum-proj + MFMA flash attention per (b,h), O^T formulation.
// Closed form: proj_w = prod_{i=0..w} cos(x_i+th_i) (w>=1); proj_0 = prod_{1..7}.
//
// TWO LDS views of proj, both written at staging:
//  kF[kt][lane]*4 halves: PRE-SWIZZLED K-fragments — lane q*16+c holds
//    K[kt*16+c][q*4+j] for q<2, lanes>=32 read an 8-half zero region.
//    -> LOADK = ONE conflict-free ds_read_b64 (256 B contiguous + broadcast).
//  vT[d][s] (stride 1032): rows 0..7 = proj^T, row 8 = ones, zero region for
//    V'-frag cols 9..15. -> LOADV = ONE ds_read_b64.
// Per wave: TWO 16-query tiles (NQ=2) share each K/V fragment -> 2 LDS
// instrs per kt serve 4 MFMAs + 8 exps; doubled ILP covers chain latency.
// mfma1: A=K-frag, B=Q-frag -> S^T C-layout == B-layout of P for mfma2.
// P = exp2(S-4.0804) (fixed shift exact in softmax, |S|log2e <= 4.0804).
// mfma2: A=V'-frag (vT), B=P -> O^T; ones-row of vT gives l[q] at lane 32+q.
// Output attnout in f16 [8192][64] for the MFMA combine kernel.
// LDS 35 KB; grid (64,8)=512 blocks = 2 blocks/CU, 8 waves/CU.
// ---------------------------------------------------------------------------
__global__ __launch_bounds__(256, 2) void attn_kernel(
        const float* __restrict__ x, const float* __restrict__ theta,
        _Float16* __restrict__ attnH) {
    __shared__ _Float16 kF[NKF];            // 16400 B
    __shared__ _Float16 vT[NV];             // 18608 B
    int bh = blockIdx.x;
    int b = bh >> 3, h = bh & 7;
    int tid = threadIdx.x;

    float th[8];
#pragma unroll
    for (int i = 0; i < 8; ++i) th[i] = theta[i];

    // zero/ones constant regions
    {
        const half4v zer = {(_Float16)0.f, (_Float16)0.f, (_Float16)0.f, (_Float16)0.f};
        const half4v one = {(_Float16)1.f, (_Float16)1.f, (_Float16)1.f, (_Float16)1.f};
        if (tid < 4) *(half4v*)&vT[VZOFF + tid * 4] = zer;
        if (tid < 2) *(half4v*)&kF[KFZ + tid * 4] = zer;
        *(half4v*)&vT[8 * VST + tid * 4] = one;     // ones row: 256 x 4 = 1024
    }

    // ---- stage: closed-form quantum heads -> kF (swizzled) + vT (transposed)
    for (int s = tid; s < S_; s += 256) {
        const float4* xp = (const float4*)(x + (((size_t)(b << 10) + s) << 6) + (h << 3));
        float4 x0 = xp[0];
        float4 x1 = xp[1];
        float c0 = __cosf(x0.x + th[0]);
        float c1 = __cosf(x0.y + th[1]);
        float c2 = __cosf(x0.z + th[2]);
        float c3 = __cosf(x0.w + th[3]);
        float c4 = __cosf(x1.x + th[4]);
        float c5 = __cosf(x1.y + th[5]);
        float c6 = __cosf(x1.z + th[6]);
        float c7 = __cosf(x1.w + th[7]);
        float e1 = c0 * c1;
        float e2 = e1 * c2;
        float e3 = e2 * c3;
        float e4 = e3 * c4;
        float e5 = e4 * c5;
        float e6 = e5 * c6;
        float e7 = e6 * c7;
        float e0 = ((c1 * c2) * (c3 * c4)) * ((c5 * c6) * c7);
        half4v lo = pack4(e0, e1, e2, e3);
        half4v hi = pack4(e4, e5, e6, e7);
        int kt = s >> 4, c = s & 15;
        *(half4v*)&kF[kt * 128 + c * 4]      = lo;  // lane (q=0,c): d0..3
        *(half4v*)&kF[kt * 128 + 64 + c * 4] = hi;  // lane (q=1,c): d4..7
        vT[0 * VST + s] = lo[0]; vT[1 * VST + s] = lo[1];
        vT[2 * VST + s] = lo[2]; vT[3 * VST + s] = lo[3];
        vT[4 * VST + s] = hi[0]; vT[5 * VST + s] = hi[1];
        vT[6 * VST + s] = hi[2]; vT[7 * VST + s] = hi[3];
    }
    __syncthreads();

    int lane = tid & 63;
    int wv   = tid >> 6;
    int col  = lane & 15;
    int quad = lane >> 4;
    int q0   = blockIdx.y * 128 + wv * 32;  // two 16-q tiles per wave

    bool lo2 = (quad < 2);

    // K-frag / Q-frag base (kF is already in fragment lane order)
    int kfa = lo2 ? (lane * 4) : KFZ;       // + kt*128
    int kstep = lo2 ? 128 : 0;

    // Q-frags: q-tile index q0>>4 and +1 are kF tiles
    half4v qfa = *(const half4v*)&kF[kfa + (q0 >> 4) * kstep];
    half4v qfb = *(const half4v*)&kF[kfa + ((q0 >> 4) + 1) * kstep];
    qfa *= (_Float16)0.51012921f;           // log2(e)/sqrt(8)
    qfb *= (_Float16)0.51012921f;

    // V'-frag: lane holds V'[key=quad*4+j][n=col] = vT[col][key]
    int vbase = (col < 9) ? (col * VST + quad * 4) : VZOFF;
    int vstep = (col < 9) ? 16 : 0;

#define LOADK(dst, t) { dst = *(const half4v*)&kF[kfa + (t) * kstep]; }
#define LOADV(dst, t) { dst = *(const half4v*)&vT[vbase + (t) * vstep]; }

    float4v oa = {0.f, 0.f, 0.f, 0.f};
    float4v ob = {0.f, 0.f, 0.f, 0.f};
    const float4v zc = {0.f, 0.f, 0.f, 0.f};
    const float SH = 4.08040428f;           // 2*sqrt(2)*log2(e)

    half4v kA, vA, kB, vB, kN, vN, kM, vM;
    LOADK(kA, 0); LOADV(vA, 0);
    LOADK(kB, 1); LOADV(vB, 1);

    for (int kt = 0; kt < 64; kt += 2) {
        // --- iter kt ---
        float4v sa = __builtin_amdgcn_mfma_f32_16x16x16f16(kA, qfa, zc, 0, 0, 0);
        float4v sb = __builtin_amdgcn_mfma_f32_16x16x16f16(kA, qfb, zc, 0, 0, 0);
        int t2 = (kt + 2) & 63;
        LOADK(kN, t2); LOADV(vN, t2);
        half4v pa = pack4(__builtin_amdgcn_exp2f(sa[0] - SH),
                          __builtin_amdgcn_exp2f(sa[1] - SH),
                          __builtin_amdgcn_exp2f(sa[2] - SH),
                          __builtin_amdgcn_exp2f(sa[3] - SH));
        half4v pb = pack4(__builtin_amdgcn_exp2f(sb[0] - SH),
                          __builtin_amdgcn_exp2f(sb[1] - SH),
                          __builtin_amdgcn_exp2f(sb[2] - SH),
                          __builtin_amdgcn_exp2f(sb[3] - SH));
        oa = __builtin_amdgcn_mfma_f32_16x16x16f16(vA, pa, oa, 0, 0, 0);
        ob = __builtin_amdgcn_mfma_f32_16x16x16f16(vA, pb, ob, 0, 0, 0);
        // --- iter kt+1 ---
        float4v sc = __builtin_amdgcn_mfma_f32_16x16x16f16(kB, qfa, zc, 0, 0, 0);
        float4v sd = __builtin_amdgcn_mfma_f32_16x16x16f16(kB, qfb, zc, 0, 0, 0);
        int t3 = (kt + 3) & 63;
        LOADK(kM, t3); LOADV(vM, t3);
        half4v pc = pack4(__builtin_amdgcn_exp2f(sc[0] - SH),
                          __builtin_amdgcn_exp2f(sc[1] - SH),
                          __builtin_amdgcn_exp2f(sc[2] - SH),
                          __builtin_amdgcn_exp2f(sc[3] - SH));
        half4v pd = pack4(__builtin_amdgcn_exp2f(sd[0] - SH),
                          __builtin_amdgcn_exp2f(sd[1] - SH),
                          __builtin_amdgcn_exp2f(sd[2] - SH),
                          __builtin_amdgcn_exp2f(sd[3] - SH));
        oa = __builtin_amdgcn_mfma_f32_16x16x16f16(vB, pc, oa, 0, 0, 0);
        ob = __builtin_amdgcn_mfma_f32_16x16x16f16(vB, pd, ob, 0, 0, 0);
        // rotate
        kA = kN; vA = vN; kB = kM; vB = vM;
    }

    // l[q] = ones-row (row 8 of O^T): lane 32+q, reg 0. Store f16 rows.
    int lsrc = 32 | col;
    {
        float l = __shfl(oa[0], lsrc, 64);
        if (lo2) {
            float inv = __builtin_amdgcn_rcpf(l);
            half4v ov = pack4(oa[0] * inv, oa[1] * inv, oa[2] * inv, oa[3] * inv);
            *(half4v*)(attnH + (((size_t)(b << 10) + q0 + col) << 6) + (h << 3) + quad * 4) = ov;
        }
    }
    {
        float l = __shfl(ob[0], lsrc, 64);
        if (lo2) {
            float inv = __builtin_amdgcn_rcpf(l);
            half4v ov = pack4(ob[0] * inv, ob[1] * inv, ob[2] * inv, ob[3] * inv);
            *(half4v*)(attnH + (((size_t)(b << 10) + q0 + 16 + col) << 6) + (h << 3) + quad * 4) = ov;
        }
    }
#undef LOADK
#undef LOADV
}

// ---------------------------------------------------------------------------
// MFMA combine: out[r,e] = sum_k A[r,k] * W[e,k], A f16 [8192][64], W f32.
// Block = 64 rows, 4 waves x 1 m-tile. W-frags loop-invariant (16 frags).
// D = A x W^T with 16 MFMAs per wave; f32 epilogue stores.
// ---------------------------------------------------------------------------
__global__ __launch_bounds__(256) void combine_kernel(
        const _Float16* __restrict__ AH, const float* __restrict__ W,
        float* __restrict__ out) {
    __shared__ _Float16 a2[64 * 68];
    __shared__ _Float16 wt[64 * 68];        // wt[k*68+e] = W[e][k]
    int r0 = blockIdx.x * 64;
    int tid = threadIdx.x;

    for (int idx = tid; idx < E_ * E_; idx += 256) {
        int e = idx >> 6, k = idx & 63;
        wt[k * 68 + e] = (_Float16)W[idx];
    }
#pragma unroll
    for (int j = 0; j < 4; ++j) {
        int off = tid * 16 + j * 4;         // 0..4095
        int row = off >> 6, k = off & 63;
        *(half4v*)&a2[row * 68 + k] = *(const half4v*)&AH[(size_t)r0 * E_ + off];
    }
    __syncthreads();

    int lane = tid & 63;
    int wv   = tid >> 6;
    int col  = lane & 15;
    int quad = lane >> 4;

    // W-frags: B[k=t*16+quad*4+j][n=e0*16+col]
    half4v wf[4][4];
#pragma unroll
    for (int t = 0; t < 4; ++t)
#pragma unroll
        for (int e = 0; e < 4; ++e) {
            int kb = (t * 16 + quad * 4) * 68 + e * 16 + col;
            half4v w_ = {wt[kb], wt[kb + 68], wt[kb + 136], wt[kb + 204]};
            wf[t][e] = w_;
        }

    float4v acc[4] = {{0,0,0,0},{0,0,0,0},{0,0,0,0},{0,0,0,0}};
#pragma unroll
    for (int t = 0; t < 4; ++t) {
        half4v af = *(const half4v*)&a2[(wv * 16 + col) * 68 + t * 16 + quad * 4];
#pragma unroll
        for (int e = 0; e < 4; ++e)
            acc[e] = __builtin_amdgcn_mfma_f32_16x16x16f16(af, wf[t][e], acc[e], 0, 0, 0);
    }

#pragma unroll
    for (int e = 0; e < 4; ++e)
#pragma unroll
        for (int r = 0; r < 4; ++r)
            out[(size_t)(r0 + wv * 16 + quad * 4 + r) * E_ + e * 16 + col] = acc[e][r];
}

// ---------------------------------------------------------------------------
extern "C" void kernel_launch(void* const* d_in, const int* in_sizes, int n_in,
                              void* d_out, int out_size, void* d_ws, size_t ws_size,
                              hipStream_t stream) {
    const float* x     = (const float*)d_in[0];   // [8,1024,64] fp32
    const float* theta = (const float*)d_in[1];   // [8]
    const float* W     = (const float*)d_in[2];   // [64,64]
    float* out = (float*)d_out;                   // [8,1024,64]

    _Float16* attnH = (_Float16*)d_ws;            // [8192][64] f16 : 1 MB

    attn_kernel<<<dim3(BH, S_ / 128), 256, 0, stream>>>(x, theta, attnH);
    combine_kernel<<<NROW / 64, 256, 0, stream>>>(attnH, W, out);
}

// Round 9
// 73.655 us; speedup vs baseline: 1.5808x; 1.0074x over previous
//
#include <hip/hip_runtime.h>

typedef _Float16 half4v __attribute__((ext_vector_type(4)));
typedef __fp16 fp16x2 __attribute__((ext_vector_type(2)));
typedef float float4v __attribute__((ext_vector_type(4)));

#define S_ 1024
#define H_ 8
#define B_ 8
#define BH 64           // B*H
#define NROW 8192       // B*S
#define E_ 64
#define VST 1032        // vT row stride (halves)

// Pack 4 floats -> half4v via v_cvt_pkrtz_f16_f32.
static __device__ inline half4v pack4(float a, float b, float c, float d) {
    union { fp16x2 f2[2]; half4v h4; } u;
    u.f2[0] = __builtin_amdgcn_cvt_pkrtz(a, b);
    u.f2[1] = __builtin_amdgcn_cvt_pkrtz(c, d);
    return u.h4;
}

// ---------------------------------------------------------------------------
// Fused quantum-proj + MFMA flash attention per (b,h), O^T formulation.
// Closed form: proj_w = prod_{i=0..w} cos(x_i+th_i) (w>=1); proj_0 = prod_{1..7}.
//
// LDS views (written once at staging):
//   kF[kt][lane*4+j]: pre-swizzled K-fragments, lanes 0..31; lanes 32..63
//     MIRROR lanes 0..31 (garbage A[k>=8] is nullified by qf=0 at quads>=2).
//   vT[d][s] stride 1032: rows 0..7 = proj^T, row 8 = ones. V'-frag cols
//     9..15 mirror cols 1..7 (junk feeds O^T rows 9..15, never read).
// -> LOADK and LOADV are each ONE ds_read_b64 at reg+immediate offset.
// K-loop fully unrolled (64): no rotation moves, no address VALU; compiler
// software-pipelines the LDS reads to fit 128 VGPRs (launch_bounds 256,4).
// mfma1: A=K-frag, B=Q-frag -> S^T (C: row=key, col=q) == B-layout of P.
// P = exp2(S) -- NO shift: uniform scaling of P cancels in o/l
//   (|S|*log2e <= 4.081 -> P in [0.059,17.0], f16- and f32-sum-safe).
// mfma2: A=V'-frag, B=P -> O^T (row=d, col=q); ones row gives l at lane 32|q.
// Grid (64,16)=1024 blocks = 4 blocks/CU (LDS 34.6 KB), 16 waves/CU.
// ---------------------------------------------------------------------------
__global__ __launch_bounds__(256, 4) void attn_kernel(
        const float* __restrict__ x, const float* __restrict__ theta,
        _Float16* __restrict__ attnH) {
    __shared__ _Float16 kF[64 * 128];       // 16384 B
    __shared__ _Float16 vT[9 * VST];        // 18576 B
    int bh = blockIdx.x;
    int b = bh >> 3, h = bh & 7;
    int tid = threadIdx.x;

    float th[8];
#pragma unroll
    for (int i = 0; i < 8; ++i) th[i] = theta[i];

    // ones row (l-trick): 256 threads x 4 halves = 1024
    {
        const half4v one = {(_Float16)1.f, (_Float16)1.f, (_Float16)1.f, (_Float16)1.f};
        *(half4v*)&vT[8 * VST + tid * 4] = one;
    }

    // ---- stage: closed-form quantum heads -> kF (swizzled) + vT (transposed)
    for (int s = tid; s < S_; s += 256) {
        const float4* xp = (const float4*)(x + (((size_t)(b << 10) + s) << 6) + (h << 3));
        float4 x0 = xp[0];
        float4 x1 = xp[1];
        float c0 = __cosf(x0.x + th[0]);
        float c1 = __cosf(x0.y + th[1]);
        float c2 = __cosf(x0.z + th[2]);
        float c3 = __cosf(x0.w + th[3]);
        float c4 = __cosf(x1.x + th[4]);
        float c5 = __cosf(x1.y + th[5]);
        float c6 = __cosf(x1.z + th[6]);
        float c7 = __cosf(x1.w + th[7]);
        float e1 = c0 * c1;
        float e2 = e1 * c2;
        float e3 = e2 * c3;
        float e4 = e3 * c4;
        float e5 = e4 * c5;
        float e6 = e5 * c6;
        float e7 = e6 * c7;
        float e0 = ((c1 * c2) * (c3 * c4)) * ((c5 * c6) * c7);
        half4v lo = pack4(e0, e1, e2, e3);
        half4v hi = pack4(e4, e5, e6, e7);
        int kt = s >> 4, c = s & 15;
        *(half4v*)&kF[kt * 128 + c * 4]      = lo;  // lane (q=0,c): d0..3
        *(half4v*)&kF[kt * 128 + 64 + c * 4] = hi;  // lane (q=1,c): d4..7
        vT[0 * VST + s] = lo[0]; vT[1 * VST + s] = lo[1];
        vT[2 * VST + s] = lo[2]; vT[3 * VST + s] = lo[3];
        vT[4 * VST + s] = hi[0]; vT[5 * VST + s] = hi[1];
        vT[6 * VST + s] = hi[2]; vT[7 * VST + s] = hi[3];
    }
    __syncthreads();

    int lane = tid & 63;
    int wv   = tid >> 6;
    int col  = lane & 15;
    int quad = lane >> 4;
    int q0   = blockIdx.y * 64 + wv * 16;   // 16 queries per wave

    bool lo2 = (quad < 2);

    // K-frag base: lanes 32..63 mirror 0..31 (A[k>=8] garbage nullified by qf)
    int kbase = (lane & 31) * 4;
    // V'-frag base: cols 9..15 mirror 1..7 (junk O^T rows never read)
    int vcol = (col < 9) ? col : (col - 8);
    int vbase = vcol * VST + quad * 4;

    // Q-frag (loop-invariant B of mfma1): quads>=2 ZERO -> kills K garbage
    half4v qf = {(_Float16)0.f, (_Float16)0.f, (_Float16)0.f, (_Float16)0.f};
    if (lo2) qf = *(const half4v*)&kF[kbase + (q0 >> 4) * 128];
    qf *= (_Float16)0.51012921f;            // log2(e)/sqrt(8)

    float4v oacc = {0.f, 0.f, 0.f, 0.f};
    const float4v zc = {0.f, 0.f, 0.f, 0.f};

#pragma unroll
    for (int kt = 0; kt < 64; ++kt) {
        half4v kf = *(const half4v*)&kF[kbase + kt * 128];
        half4v vf = *(const half4v*)&vT[vbase + kt * 16];
        float4v st = __builtin_amdgcn_mfma_f32_16x16x16f16(kf, qf, zc, 0, 0, 0);
        half4v pf = pack4(__builtin_amdgcn_exp2f(st[0]),
                          __builtin_amdgcn_exp2f(st[1]),
                          __builtin_amdgcn_exp2f(st[2]),
                          __builtin_amdgcn_exp2f(st[3]));
        oacc = __builtin_amdgcn_mfma_f32_16x16x16f16(vf, pf, oacc, 0, 0, 0);
    }

    // l[q] = ones-row (row 8 of O^T): lane 32|q, reg 0.
    float l = __shfl(oacc[0], 32 | col, 64);
    if (lo2) {
        float inv = __builtin_amdgcn_rcpf(l);
        half4v ov = pack4(oacc[0] * inv, oacc[1] * inv, oacc[2] * inv, oacc[3] * inv);
        *(half4v*)(attnH + (((size_t)(b << 10) + q0 + col) << 6) + (h << 3) + quad * 4) = ov;
    }
}

// ---------------------------------------------------------------------------
// MFMA combine: out[r,e] = sum_k A[r,k] * W[e,k], A f16 [8192][64], W f32.
// Block = 64 rows, 4 waves. W-frags loop-invariant; 16 MFMAs per wave.
// ---------------------------------------------------------------------------
__global__ __launch_bounds__(256) void combine_kernel(
        const _Float16* __restrict__ AH, const float* __restrict__ W,
        float* __restrict__ out) {
    __shared__ _Float16 a2[64 * 68];
    __shared__ _Float16 wt[64 * 68];        // wt[k*68+e] = W[e][k]
    int r0 = blockIdx.x * 64;
    int tid = threadIdx.x;

    for (int idx = tid; idx < E_ * E_; idx += 256) {
        int e = idx >> 6, k = idx & 63;
        wt[k * 68 + e] = (_Float16)W[idx];
    }
#pragma unroll
    for (int j = 0; j < 4; ++j) {
        int off = tid * 16 + j * 4;         // 0..4095
        int row = off >> 6, k = off & 63;
        *(half4v*)&a2[row * 68 + k] = *(const half4v*)&AH[(size_t)r0 * E_ + off];
    }
    __syncthreads();

    int lane = tid & 63;
    int wv   = tid >> 6;
    int col  = lane & 15;
    int quad = lane >> 4;

    // W-frags: B[k=t*16+quad*4+j][n=e0*16+col]
    half4v wf[4][4];
#pragma unroll
    for (int t = 0; t < 4; ++t)
#pragma unroll
        for (int e = 0; e < 4; ++e) {
            int kb = (t * 16 + quad * 4) * 68 + e * 16 + col;
            half4v w_ = {wt[kb], wt[kb + 68], wt[kb + 136], wt[kb + 204]};
            wf[t][e] = w_;
        }

    float4v acc[4] = {{0,0,0,0},{0,0,0,0},{0,0,0,0},{0,0,0,0}};
#pragma unroll
    for (int t = 0; t < 4; ++t) {
        half4v af = *(const half4v*)&a2[(wv * 16 + col) * 68 + t * 16 + quad * 4];
#pragma unroll
        for (int e = 0; e < 4; ++e)
            acc[e] = __builtin_amdgcn_mfma_f32_16x16x16f16(af, wf[t][e], acc[e], 0, 0, 0);
    }

#pragma unroll
    for (int e = 0; e < 4; ++e)
#pragma unroll
        for (int r = 0; r < 4; ++r)
            out[(size_t)(r0 + wv * 16 + quad * 4 + r) * E_ + e * 16 + col] = acc[e][r];
}

// ---------------------------------------------------------------------------
extern "C" void kernel_launch(void* const* d_in, const int* in_sizes, int n_in,
                              void* d_out, int out_size, void* d_ws, size_t ws_size,
                              hipStream_t stream) {
    const float* x     = (const float*)d_in[0];   // [8,1024,64] fp32
    const float* theta = (const float*)d_in[1];   // [8]
    const float* W     = (const float*)d_in[2];   // [64,64]
    float* out = (float*)d_out;                   // [8,1024,64]

    _Float16* attnH = (_Float16*)d_ws;            // [8192][64] f16 : 1 MB

    attn_kernel<<<dim3(BH, S_ / 64), 256, 0, stream>>>(x, theta, attnH);
    combine_kernel<<<NROW / 64, 256, 0, stream>>>(attnH, W, out);
}

// Round 10
// 73.021 us; speedup vs baseline: 1.5946x; 1.0087x over previous
//
#include <hip/hip_runtime.h>

typedef _Float16 half4v __attribute__((ext_vector_type(4)));
typedef __fp16 fp16x2 __attribute__((ext_vector_type(2)));
typedef float float4v __attribute__((ext_vector_type(4)));

#define S_ 1024
#define H_ 8
#define B_ 8
#define BH 64           // B*H
#define NROW 8192       // B*S
#define E_ 64
#define VST 1032        // vT row stride (halves)

// Pack 4 floats -> half4v via v_cvt_pkrtz_f16_f32.
static __device__ inline half4v pack4(float a, float b, float c, float d) {
    union { fp16x2 f2[2]; half4v h4; } u;
    u.f2[0] = __builtin_amdgcn_cvt_pkrtz(a, b);
    u.f2[1] = __builtin_amdgcn_cvt_pkrtz(c, d);
    return u.h4;
}

// ---------------------------------------------------------------------------
// Fused quantum-proj + MFMA flash attention per (b,h), O^T formulation.
// Closed form: proj_w = prod_{i=0..w} cos(x_i+th_i) (w>=1); proj_0 = prod_{1..7}.
//
// LDS views (written once at staging):
//   kF[kt][lane*4+j]: pre-swizzled K-fragments, lanes 0..31; lanes 32..63
//     MIRROR lanes 0..31 (garbage A[k>=8] nullified by qf=0 at quads>=2).
//   vT[d][s] stride 1032: rows 0..7 = proj^T, row 8 = ones; V'-frag cols
//     9..15 mirror cols 1..7 (junk feeds O^T rows 9..15, never read).
// -> LOADK / LOADV are each ONE ds_read_b64 at reg+immediate offset.
//
// KEY CHANGE (R10): each wave runs FOUR independent key-range chains
// (keys kt+0/16/32/48 per step), each with its own accumulator, merged at
// the end. Prior rounds all had exactly 4 independent chains per SIMD
// (structural invariant of tiles/CU=16) -- not enough to hide the
// mfma1->exp->pack->mfma2 serial latency (~150 cyc/kt). J=4 chains/wave
// x 4 waves/SIMD = 16 chains/SIMD. BFS-ordered body gives the scheduler
// the ILP explicitly. No extra LDS, no occupancy change.
//
// mfma1: A=K-frag, B=Q-frag -> S^T (C: row=key, col=q) == B-layout of P.
// P = exp2(S) -- no shift needed: uniform scaling cancels in o/l.
// mfma2: A=V'-frag, B=P -> O^T (row=d, col=q); ones row gives l at lane 32|q.
// Grid (64,16)=1024 blocks = 4 blocks/CU (LDS 34.6 KB), 16 waves/CU.
// ---------------------------------------------------------------------------
__global__ __launch_bounds__(256, 4) void attn_kernel(
        const float* __restrict__ x, const float* __restrict__ theta,
        _Float16* __restrict__ attnH) {
    __shared__ _Float16 kF[64 * 128];       // 16384 B
    __shared__ _Float16 vT[9 * VST];        // 18576 B
    int bh = blockIdx.x;
    int b = bh >> 3, h = bh & 7;
    int tid = threadIdx.x;

    float th[8];
#pragma unroll
    for (int i = 0; i < 8; ++i) th[i] = theta[i];

    // ones row (l-trick): 256 threads x 4 halves = 1024
    {
        const half4v one = {(_Float16)1.f, (_Float16)1.f, (_Float16)1.f, (_Float16)1.f};
        *(half4v*)&vT[8 * VST + tid * 4] = one;
    }

    // ---- stage: closed-form quantum heads -> kF (swizzled) + vT (transposed)
    for (int s = tid; s < S_; s += 256) {
        const float4* xp = (const float4*)(x + (((size_t)(b << 10) + s) << 6) + (h << 3));
        float4 x0 = xp[0];
        float4 x1 = xp[1];
        float c0 = __cosf(x0.x + th[0]);
        float c1 = __cosf(x0.y + th[1]);
        float c2 = __cosf(x0.z + th[2]);
        float c3 = __cosf(x0.w + th[3]);
        float c4 = __cosf(x1.x + th[4]);
        float c5 = __cosf(x1.y + th[5]);
        float c6 = __cosf(x1.z + th[6]);
        float c7 = __cosf(x1.w + th[7]);
        float e1 = c0 * c1;
        float e2 = e1 * c2;
        float e3 = e2 * c3;
        float e4 = e3 * c4;
        float e5 = e4 * c5;
        float e6 = e5 * c6;
        float e7 = e6 * c7;
        float e0 = ((c1 * c2) * (c3 * c4)) * ((c5 * c6) * c7);
        half4v lo = pack4(e0, e1, e2, e3);
        half4v hi = pack4(e4, e5, e6, e7);
        int kt = s >> 4, c = s & 15;
        *(half4v*)&kF[kt * 128 + c * 4]      = lo;  // lane (q=0,c): d0..3
        *(half4v*)&kF[kt * 128 + 64 + c * 4] = hi;  // lane (q=1,c): d4..7
        vT[0 * VST + s] = lo[0]; vT[1 * VST + s] = lo[1];
        vT[2 * VST + s] = lo[2]; vT[3 * VST + s] = lo[3];
        vT[4 * VST + s] = hi[0]; vT[5 * VST + s] = hi[1];
        vT[6 * VST + s] = hi[2]; vT[7 * VST + s] = hi[3];
    }
    __syncthreads();

    int lane = tid & 63;
    int wv   = tid >> 6;
    int col  = lane & 15;
    int quad = lane >> 4;
    int q0   = blockIdx.y * 64 + wv * 16;   // 16 queries per wave

    bool lo2 = (quad < 2);

    // K-frag base: lanes 32..63 mirror 0..31 (A[k>=8] garbage nullified by qf)
    int kbase = (lane & 31) * 4;
    // V'-frag base: cols 9..15 mirror 1..7 (junk O^T rows never read)
    int vcol = (col < 9) ? col : (col - 8);
    int vbase = vcol * VST + quad * 4;

    // Q-frag (loop-invariant B of mfma1): quads>=2 ZERO -> kills K garbage
    half4v qf = {(_Float16)0.f, (_Float16)0.f, (_Float16)0.f, (_Float16)0.f};
    if (lo2) qf = *(const half4v*)&kF[kbase + (q0 >> 4) * 128];
    qf *= (_Float16)0.51012921f;            // log2(e)/sqrt(8)

    const float4v zc = {0.f, 0.f, 0.f, 0.f};
    float4v o0 = zc, o1 = zc, o2 = zc, o3 = zc;

#pragma unroll
    for (int kt = 0; kt < 16; ++kt) {
        // ---- BFS: 4 independent chains over key quarters ----
        half4v k0 = *(const half4v*)&kF[kbase + (kt +  0) * 128];
        half4v k1 = *(const half4v*)&kF[kbase + (kt + 16) * 128];
        half4v k2 = *(const half4v*)&kF[kbase + (kt + 32) * 128];
        half4v k3 = *(const half4v*)&kF[kbase + (kt + 48) * 128];
        half4v v0 = *(const half4v*)&vT[vbase + (kt +  0) * 16];
        half4v v1 = *(const half4v*)&vT[vbase + (kt + 16) * 16];
        half4v v2 = *(const half4v*)&vT[vbase + (kt + 32) * 16];
        half4v v3 = *(const half4v*)&vT[vbase + (kt + 48) * 16];
        float4v s0 = __builtin_amdgcn_mfma_f32_16x16x16f16(k0, qf, zc, 0, 0, 0);
        float4v s1 = __builtin_amdgcn_mfma_f32_16x16x16f16(k1, qf, zc, 0, 0, 0);
        float4v s2 = __builtin_amdgcn_mfma_f32_16x16x16f16(k2, qf, zc, 0, 0, 0);
        float4v s3 = __builtin_amdgcn_mfma_f32_16x16x16f16(k3, qf, zc, 0, 0, 0);
        half4v p0 = pack4(__builtin_amdgcn_exp2f(s0[0]), __builtin_amdgcn_exp2f(s0[1]),
                          __builtin_amdgcn_exp2f(s0[2]), __builtin_amdgcn_exp2f(s0[3]));
        half4v p1 = pack4(__builtin_amdgcn_exp2f(s1[0]), __builtin_amdgcn_exp2f(s1[1]),
                          __builtin_amdgcn_exp2f(s1[2]), __builtin_amdgcn_exp2f(s1[3]));
        half4v p2 = pack4(__builtin_amdgcn_exp2f(s2[0]), __builtin_amdgcn_exp2f(s2[1]),
                          __builtin_amdgcn_exp2f(s2[2]), __builtin_amdgcn_exp2f(s2[3]));
        half4v p3 = pack4(__builtin_amdgcn_exp2f(s3[0]), __builtin_amdgcn_exp2f(s3[1]),
                          __builtin_amdgcn_exp2f(s3[2]), __builtin_amdgcn_exp2f(s3[3]));
        o0 = __builtin_amdgcn_mfma_f32_16x16x16f16(v0, p0, o0, 0, 0, 0);
        o1 = __builtin_amdgcn_mfma_f32_16x16x16f16(v1, p1, o1, 0, 0, 0);
        o2 = __builtin_amdgcn_mfma_f32_16x16x16f16(v2, p2, o2, 0, 0, 0);
        o3 = __builtin_amdgcn_mfma_f32_16x16x16f16(v3, p3, o3, 0, 0, 0);
    }

    float4v oacc;
#pragma unroll
    for (int r = 0; r < 4; ++r) oacc[r] = (o0[r] + o1[r]) + (o2[r] + o3[r]);

    // l[q] = ones-row (row 8 of O^T): lane 32|q, reg 0.
    float l = __shfl(oacc[0], 32 | col, 64);
    if (lo2) {
        float inv = __builtin_amdgcn_rcpf(l);
        half4v ov = pack4(oacc[0] * inv, oacc[1] * inv, oacc[2] * inv, oacc[3] * inv);
        *(half4v*)(attnH + (((size_t)(b << 10) + q0 + col) << 6) + (h << 3) + quad * 4) = ov;
    }
}

// ---------------------------------------------------------------------------
// MFMA combine: out[r,e] = sum_k A[r,k] * W[e,k], A f16 [8192][64], W f32.
// Block = 64 rows, 4 waves. W-frags loop-invariant; 16 MFMAs per wave.
// ---------------------------------------------------------------------------
__global__ __launch_bounds__(256) void combine_kernel(
        const _Float16* __restrict__ AH, const float* __restrict__ W,
        float* __restrict__ out) {
    __shared__ _Float16 a2[64 * 68];
    __shared__ _Float16 wt[64 * 68];        // wt[k*68+e] = W[e][k]
    int r0 = blockIdx.x * 64;
    int tid = threadIdx.x;

    for (int idx = tid; idx < E_ * E_; idx += 256) {
        int e = idx >> 6, k = idx & 63;
        wt[k * 68 + e] = (_Float16)W[idx];
    }
#pragma unroll
    for (int j = 0; j < 4; ++j) {
        int off = tid * 16 + j * 4;         // 0..4095
        int row = off >> 6, k = off & 63;
        *(half4v*)&a2[row * 68 + k] = *(const half4v*)&AH[(size_t)r0 * E_ + off];
    }
    __syncthreads();

    int lane = tid & 63;
    int wv   = tid >> 6;
    int col  = lane & 15;
    int quad = lane >> 4;

    // W-frags: B[k=t*16+quad*4+j][n=e0*16+col]
    half4v wf[4][4];
#pragma unroll
    for (int t = 0; t < 4; ++t)
#pragma unroll
        for (int e = 0; e < 4; ++e) {
            int kb = (t * 16 + quad * 4) * 68 + e * 16 + col;
            half4v w_ = {wt[kb], wt[kb + 68], wt[kb + 136], wt[kb + 204]};
            wf[t][e] = w_;
        }

    float4v acc[4] = {{0,0,0,0},{0,0,0,0},{0,0,0,0},{0,0,0,0}};
#pragma unroll
    for (int t = 0; t < 4; ++t) {
        half4v af = *(const half4v*)&a2[(wv * 16 + col) * 68 + t * 16 + quad * 4];
#pragma unroll
        for (int e = 0; e < 4; ++e)
            acc[e] = __builtin_amdgcn_mfma_f32_16x16x16f16(af, wf[t][e], acc[e], 0, 0, 0);
    }

#pragma unroll
    for (int e = 0; e < 4; ++e)
#pragma unroll
        for (int r = 0; r < 4; ++r)
            out[(size_t)(r0 + wv * 16 + quad * 4 + r) * E_ + e * 16 + col] = acc[e][r];
}

// ---------------------------------------------------------------------------
extern "C" void kernel_launch(void* const* d_in, const int* in_sizes, int n_in,
                              void* d_out, int out_size, void* d_ws, size_t ws_size,
                              hipStream_t stream) {
    const float* x     = (const float*)d_in[0];   // [8,1024,64] fp32
    const float* theta = (const float*)d_in[1];   // [8]
    const float* W     = (const float*)d_in[2];   // [64,64]
    float* out = (float*)d_out;                   // [8,1024,64]

    _Float16* attnH = (_Float16*)d_ws;            // [8192][64] f16 : 1 MB

    attn_kernel<<<dim3(BH, S_ / 64), 256, 0, stream>>>(x, theta, attnH);
    combine_kernel<<<NROW / 64, 256, 0, stream>>>(attnH, W, out);
}